// Round 4
// baseline (977.422 us; speedup 1.0000x reference)
//
#include <hip/hip_runtime.h>

// VectorQuantizer: x [32768, 256] fp32, codebook [1024, 256] fp32.
// Harness reference recomputes in float32 (R3: absmax==0 with fp32-replica):
//   d[n,k] = fl( fl( ||x_n||^2 - 2*dot(x_n,c_k) ) + ||c_k||^2 )  all fp32
//   idx = np.argmin (first-index ties), out = codebook[idx]
// Replica invariants (DO NOT BREAK):
//  - dot: single sequential fp32 FMA chain per (n,k), d ascending.
//  - q = (S - 2*acc) + cn : two fp32 roundings in this order.
//  - S from fp32 squares summed in fp64 (exact order irrelevant - R3 proved
//    S bits are argmin-invariant), rounded once to fp32.
//  - within-thread k ascending + strict < ; cross-thread tie-break on index.
//
// R4 structure: x-tile persistent in LDS (staged once), codebook streamed
// from global (1 MB, L2-resident) -> ZERO barriers in the hot K-loop, so
// global loads software-pipeline. Register tile 4n x 8k: 128 FMA per
// (4 ds_read_b128 + 8 global_load_dwordx4). a-reads hit disjoint bank quads
// (row stride 260 = 4 mod 32, 4 rows/wave -> banks 0-3/4-7/8-11/12-15).

#define D         256
#define K_TOTAL   1024
#define N_ROWS    32768
#define TM        64
#define XS_STRIDE 260         // 256 + 4: rows 16B-aligned, a-reads conflict-free

// ---------------- kernel 1: codebook squared norms ----------------
__global__ void cnorm_kernel(const float* __restrict__ cb, float* __restrict__ cnorm) {
    const int wave = threadIdx.x >> 6;
    const int lane = threadIdx.x & 63;
    const int k    = blockIdx.x * 4 + wave;       // 0..1023
    float4 v = *(const float4*)(cb + (size_t)k * D + lane * 4);
    float sx = v.x * v.x, sy = v.y * v.y, sz = v.z * v.z, sw = v.w * v.w;
    double s = (double)sx + (double)sy + (double)sz + (double)sw;
    #pragma unroll
    for (int off = 32; off > 0; off >>= 1)
        s += __shfl_down(s, off, 64);
    if (lane == 0) cnorm[k] = (float)s;
}

// ---------------- kernel 2: fused distance + argmin + gather ----------------
__global__ __launch_bounds__(256, 2)
void vq_kernel(const float* __restrict__ x, const float* __restrict__ cb,
               const float* __restrict__ cnorm, float* __restrict__ out) {
    __shared__ float  xs[TM * XS_STRIDE];     // 66560 B x-tile [64 n][256 d]
    __shared__ double sred[TM][4];            // 2 KB row-norm partials
    __shared__ float  red_val[TM * 16];       // 4 KB
    __shared__ int    red_idx[TM * 16];       // 4 KB
    __shared__ int    best_idx[TM];

    const int tid = threadIdx.x;
    const int tx  = tid & 15;                 // k-owner: k = tx + 16*(8*jg + j)
    const int ty  = tid >> 4;                 // n-owner: n = ty + 16*i
    const int n0  = blockIdx.x * TM;

    // ---- stage x-tile once (coalesced 16B loads) ----
    #pragma unroll
    for (int r = 0; r < 16; ++r) {
        const int idx  = tid + 256 * r;       // float4 index 0..4095
        const int row  = idx >> 6;
        const int col4 = idx & 63;
        float4 v = *(const float4*)(x + (size_t)(n0 + row) * D + col4 * 4);
        *(float4*)(xs + row * XS_STRIDE + col4 * 4) = v;
    }
    __syncthreads();

    // ---- row norms from the LDS tile: fp32 squares, fp64 accumulate ----
    {
        const int r = tid >> 2, seg = tid & 3;
        const float* p = xs + r * XS_STRIDE + seg * 64;
        double s = 0.0;
        #pragma unroll
        for (int d = 0; d < 64; d += 4) {
            float4 v = *(const float4*)(p + d);
            float a0 = v.x * v.x, a1 = v.y * v.y, a2 = v.z * v.z, a3 = v.w * v.w;
            s += (double)a0 + (double)a1 + (double)a2 + (double)a3;
        }
        sred[r][seg] = s;
    }
    __syncthreads();

    float S[4];
    const float* arow[4];
    #pragma unroll
    for (int i = 0; i < 4; ++i) {
        const int rr = ty + 16 * i;
        S[i]    = (float)(sred[rr][0] + sred[rr][1] + sred[rr][2] + sred[rr][3]);
        arow[i] = xs + rr * XS_STRIDE;
    }

    float runmin[4];
    int   runidx[4];
    #pragma unroll
    for (int i = 0; i < 4; ++i) { runmin[i] = 1e30f; runidx[i] = 0; }

    // ---- barrier-free K loop: 8 groups of 8 codes per thread ----
    for (int jg = 0; jg < 8; ++jg) {
        int kk[8];
        const float* brow[8];
        #pragma unroll
        for (int j = 0; j < 8; ++j) {
            kk[j]   = tx + 16 * (8 * jg + j);          // ascending k in (jg, j)
            brow[j] = cb + (size_t)kk[j] * D;
        }

        float acc[4][8];
        #pragma unroll
        for (int i = 0; i < 4; ++i)
            #pragma unroll
            for (int j = 0; j < 8; ++j) acc[i][j] = 0.f;

        // Sequential fp32 FMA chain per (i,j), d ascending — replica of the
        // reference's fp32 accumulation. Do NOT split accumulators.
        #pragma unroll 2
        for (int dd = 0; dd < D; dd += 4) {
            float4 b[8], a[4];
            #pragma unroll
            for (int j = 0; j < 8; ++j) b[j] = *(const float4*)(brow[j] + dd);
            #pragma unroll
            for (int i = 0; i < 4; ++i) a[i] = *(const float4*)(arow[i] + dd);
            #pragma unroll
            for (int i = 0; i < 4; ++i)
                #pragma unroll
                for (int j = 0; j < 8; ++j) {
                    acc[i][j] += a[i].x * b[j].x;
                    acc[i][j] += a[i].y * b[j].y;
                    acc[i][j] += a[i].z * b[j].z;
                    acc[i][j] += a[i].w * b[j].w;
                }
        }

        #pragma unroll
        for (int j = 0; j < 8; ++j) {
            const float cn = cnorm[kk[j]];
            #pragma unroll
            for (int i = 0; i < 4; ++i) {
                const float t = S[i] - 2.0f * acc[i][j];   // rounding 1 (2*acc exact)
                const float q = t + cn;                    // rounding 2
                if (q < runmin[i]) { runmin[i] = q; runidx[i] = kk[j]; }
            }
        }
    }

    // ---- cross-thread argmin merge (16 tx candidates per row) ----
    __syncthreads();
    #pragma unroll
    for (int i = 0; i < 4; ++i) {
        const int row = ty + 16 * i;
        red_val[row * 16 + tx] = runmin[i];
        red_idx[row * 16 + tx] = runidx[i];
    }
    __syncthreads();
    if (tid < TM) {
        const int row = tid;
        float bv = red_val[row * 16];
        int   bi = red_idx[row * 16];
        #pragma unroll
        for (int t = 1; t < 16; ++t) {
            const float v = red_val[row * 16 + t];
            const int  ix = red_idx[row * 16 + t];
            if (v < bv || (v == bv && ix < bi)) { bv = v; bi = ix; }
        }
        best_idx[row] = bi;
    }
    __syncthreads();

    // ---- gather winning codebook rows -> out ----
    {
        const int col4 = tid & 63;
        const int row  = tid >> 6;
        #pragma unroll
        for (int r = 0; r < 16; ++r) {
            const int rr = row + 4 * r;
            const int k  = best_idx[rr];
            float4 v = *(const float4*)(cb + (size_t)k * D + col4 * 4);
            *(float4*)(out + (size_t)(n0 + rr) * D + col4 * 4) = v;
        }
    }
}

extern "C" void kernel_launch(void* const* d_in, const int* in_sizes, int n_in,
                              void* d_out, int out_size, void* d_ws, size_t ws_size,
                              hipStream_t stream) {
    const float* x  = (const float*)d_in[0];   // [32768, 256]
    const float* cb = (const float*)d_in[1];   // [1024, 256]
    float* out   = (float*)d_out;              // [32768, 256]
    float* cnorm = (float*)d_ws;               // 1024 fp32 scratch

    const int N = in_sizes[0] / D;             // 32768
    cnorm_kernel<<<K_TOTAL / 4, 256, 0, stream>>>(cb, cnorm);
    vq_kernel<<<N / TM, 256, 0, stream>>>(x, cb, cnorm, out);
}

// Round 5
// 580.169 us; speedup vs baseline: 1.6847x; 1.6847x over previous
//
#include <hip/hip_runtime.h>

// VectorQuantizer: x [32768, 256] fp32, codebook [1024, 256] fp32.
// Harness reference recomputes in float32 (R3: absmax==0 with fp32-replica):
//   d[n,k] = fl( fl( ||x_n||^2 - 2*dot(x_n,c_k) ) + ||c_k||^2 )  all fp32
//   idx = np.argmin (first-index ties), out = codebook[idx]
// Replica invariants (DO NOT BREAK):
//  - dot: single sequential fp32 FMA chain per (n,k), d ascending.
//  - q = (S - 2*acc) + cn : two fp32 roundings in this order.
//  - S: fp32 squares, fp64-accumulated (order-invariant, R3-proven), 1 rounding.
//  - within-thread k ascending + strict < ; cross-thread tie-break on index.
//
// R5 structure (R4 post-mortem: codebook MUST stream via LDS -- global k-owner
// loads are 16-way address-divergent and swamp L1; x from global is fine, only
// 4 distinct broadcast addresses/wave):
//  - TM=32 rows/block -> grid 1024 = 4 blocks/CU (16 waves/CU, 2x R3).
//  - 32-code LDS chunks (33.3 KB); reductions OVERLAID into dead cs after the
//    K loop; in-block row norms. Total ~35.6 KB -> 4 blocks/CU fits.
//  - 2n x 2k register tile: 16 FMA : 2 global-a : 2 lds-b per dd-step.

#define D         256
#define K_TOTAL   1024
#define N_ROWS    32768
#define TM        32          // n-rows per block
#define TN        32          // codes per LDS chunk
#define NCHUNK    (K_TOTAL / TN)
#define CS_STRIDE 260         // 256+4: rows 16B-aligned; reads 2-way (free)

// ---------------- kernel 1: codebook squared norms ----------------
__global__ void cnorm_kernel(const float* __restrict__ cb, float* __restrict__ cnorm) {
    const int wave = threadIdx.x >> 6;
    const int lane = threadIdx.x & 63;
    const int k    = blockIdx.x * 4 + wave;       // 0..1023
    float4 v = *(const float4*)(cb + (size_t)k * D + lane * 4);
    float sx = v.x * v.x, sy = v.y * v.y, sz = v.z * v.z, sw = v.w * v.w;
    double s = (double)sx + (double)sy + (double)sz + (double)sw;
    #pragma unroll
    for (int off = 32; off > 0; off >>= 1)
        s += __shfl_down(s, off, 64);
    if (lane == 0) cnorm[k] = (float)s;
}

// ---------------- kernel 2: fused distance + argmin + gather ----------------
__global__ __launch_bounds__(256, 4)
void vq_kernel(const float* __restrict__ x, const float* __restrict__ cb,
               const float* __restrict__ cnorm, float* __restrict__ out) {
    __shared__ float  cs[TN * CS_STRIDE];   // 33280 B codebook chunk [32 k][256 d]
    __shared__ double sred[TM][8];          // 2 KB row-norm partials
    __shared__ int    best_idx[TM];         // 128 B

    const int tid = threadIdx.x;
    const int tx  = tid & 15;               // k-owner: k = kc*32 + tx + 16*j
    const int ty  = tid >> 4;               // n-owner: rows ty + 16*i
    const int n0  = blockIdx.x * TM;

    // ---- in-block row norms: fp32 squares, fp64 partials (8 threads/row) ----
    {
        const int r = tid >> 3, seg = tid & 7;          // r: 0..31, seg: 0..7
        const float* p = x + (size_t)(n0 + r) * D + seg * 32;
        double s = 0.0;
        #pragma unroll
        for (int d = 0; d < 32; d += 4) {
            float4 v = *(const float4*)(p + d);
            float a0 = v.x * v.x, a1 = v.y * v.y, a2 = v.z * v.z, a3 = v.w * v.w;
            s += (double)a0 + (double)a1 + (double)a2 + (double)a3;
        }
        sred[r][seg] = s;
    }
    __syncthreads();

    float S[2];
    const float* arow[2];
    #pragma unroll
    for (int i = 0; i < 2; ++i) {
        const int rr = ty + 16 * i;
        double s = 0.0;
        #pragma unroll
        for (int t = 0; t < 8; ++t) s += sred[rr][t];
        S[i]    = (float)s;                  // single fp64->fp32 rounding
        arow[i] = x + (size_t)(n0 + rr) * D;
    }

    float runmin[2];
    int   runidx[2];
    #pragma unroll
    for (int i = 0; i < 2; ++i) { runmin[i] = 1e30f; runidx[i] = 0; }

    for (int kc = 0; kc < NCHUNK; ++kc) {
        const int k0 = kc * TN;

        __syncthreads();   // protect cs from previous chunk's readers
        {   // stage 32 codebook rows: coalesced 16B global reads (L2-resident)
            #pragma unroll
            for (int r = 0; r < 8; ++r) {
                const int idx  = tid + 256 * r;      // float4 index 0..2047
                const int row  = idx >> 6;
                const int col4 = idx & 63;
                float4 v = *(const float4*)(cb + (size_t)(k0 + row) * D + col4 * 4);
                *(float4*)(cs + row * CS_STRIDE + col4 * 4) = v;
            }
        }
        __syncthreads();

        float acc[2][2];
        #pragma unroll
        for (int i = 0; i < 2; ++i)
            #pragma unroll
            for (int j = 0; j < 2; ++j) acc[i][j] = 0.f;

        // Sequential fp32 FMA chain per (i,j), d ascending — fp32 replica.
        #pragma unroll 4
        for (int dd = 0; dd < D; dd += 4) {
            float4 a[2], b[2];
            #pragma unroll
            for (int j = 0; j < 2; ++j) b[j] = *(const float4*)(cs + (tx + 16 * j) * CS_STRIDE + dd);
            #pragma unroll
            for (int i = 0; i < 2; ++i) a[i] = *(const float4*)(arow[i] + dd);
            #pragma unroll
            for (int i = 0; i < 2; ++i)
                #pragma unroll
                for (int j = 0; j < 2; ++j) {
                    acc[i][j] += a[i].x * b[j].x;
                    acc[i][j] += a[i].y * b[j].y;
                    acc[i][j] += a[i].z * b[j].z;
                    acc[i][j] += a[i].w * b[j].w;
                }
        }

        // q = (S - 2*acc) + cn, two fp32 roundings; ascending k, strict <
        #pragma unroll
        for (int j = 0; j < 2; ++j) {
            const int k = k0 + tx + 16 * j;
            const float cn = cnorm[k];
            #pragma unroll
            for (int i = 0; i < 2; ++i) {
                const float t = S[i] - 2.0f * acc[i][j];
                const float q = t + cn;
                if (q < runmin[i]) { runmin[i] = q; runidx[i] = k; }
            }
        }
    }

    // ---- cross-thread argmin merge, arrays overlaid into dead cs ----
    __syncthreads();                         // last chunk's cs readers done
    float* red_val = cs;                     // 512 floats
    int*   red_idx = (int*)(cs + 512);       // 512 ints
    #pragma unroll
    for (int i = 0; i < 2; ++i) {
        const int row = ty + 16 * i;
        red_val[row * 16 + tx] = runmin[i];
        red_idx[row * 16 + tx] = runidx[i];
    }
    __syncthreads();
    if (tid < TM) {
        const int row = tid;
        float bv = red_val[row * 16];
        int   bi = red_idx[row * 16];
        #pragma unroll
        for (int t = 1; t < 16; ++t) {
            const float v = red_val[row * 16 + t];
            const int  ix = red_idx[row * 16 + t];
            if (v < bv || (v == bv && ix < bi)) { bv = v; bi = ix; }
        }
        best_idx[row] = bi;
    }
    __syncthreads();

    // ---- gather winning codebook rows -> out, coalesced 16B ----
    {
        const int col4 = tid & 63;
        const int row  = tid >> 6;
        #pragma unroll
        for (int r = 0; r < 8; ++r) {
            const int rr = row + 4 * r;
            const int k  = best_idx[rr];
            float4 v = *(const float4*)(cb + (size_t)k * D + col4 * 4);
            *(float4*)(out + (size_t)(n0 + rr) * D + col4 * 4) = v;
        }
    }
}

extern "C" void kernel_launch(void* const* d_in, const int* in_sizes, int n_in,
                              void* d_out, int out_size, void* d_ws, size_t ws_size,
                              hipStream_t stream) {
    const float* x  = (const float*)d_in[0];   // [32768, 256]
    const float* cb = (const float*)d_in[1];   // [1024, 256]
    float* out   = (float*)d_out;              // [32768, 256]
    float* cnorm = (float*)d_ws;               // 1024 fp32 scratch

    const int N = in_sizes[0] / D;             // 32768
    cnorm_kernel<<<K_TOTAL / 4, 256, 0, stream>>>(cb, cnorm);
    vq_kernel<<<N / TM, 256, 0, stream>>>(x, cb, cnorm, out);
}